// Round 12
// baseline (236.538 us; speedup 1.0000x reference)
//
#include <hip/hip_runtime.h>

#define K_CODES 1024
#define DIMS    256
#define NROWS   32768   // B*H*W = 32*32*32

// ---------------- main-path geometry ----------------
#define NGROUPS       4      // code groups of 256 (4 codes per lane)
#define ROWS_PER_WAVE 8      // 4096 slices x 4 groups = 16384 waves, 4096 blocks
#define RP            8      // rows per (single) pass

// ws layout (float units)
#define WS_ET    0
#define WS_ESQ   (WS_ET  + DIMS * K_CODES)        // 262144 (et4: 64 x 1024 float4)
#define WS_XSQ   (WS_ESQ + K_CODES)               // +1024
#define WS_CAND  (WS_XSQ + NROWS)                 // +32768
#define WS_NEED_FLOATS (WS_CAND + NGROUPS * NROWS * 2)
#define WS_NEED_BYTES  ((size_t)WS_NEED_FLOATS * 4)

// ---------------------------------------------------------------------------
// numpy-bitwise sum of squares of a 256-element row (verified round 2).
// ---------------------------------------------------------------------------
__device__ __forceinline__ float sq_at(const float* p, int d, int stride) {
#pragma clang fp contract(off)
    const float v = p[(size_t)d * stride];
    return v * v;
}

__device__ __forceinline__ float np_block_sq(const float* p, int stride, int o, int n) {
#pragma clang fp contract(off)
    float r[8];
    #pragma unroll
    for (int k = 0; k < 8; ++k) r[k] = sq_at(p, o + k, stride);
    const int n8 = n - (n % 8);
    for (int i = 8; i < n8; i += 8) {
        #pragma unroll
        for (int k = 0; k < 8; ++k) r[k] = r[k] + sq_at(p, o + i + k, stride);
    }
    float res = ((r[0] + r[1]) + (r[2] + r[3])) + ((r[4] + r[5]) + (r[6] + r[7]));
    for (int i = n8; i < n; ++i) res = res + sq_at(p, o + i, stride);
    return res;
}

__device__ __forceinline__ float np_sumsq_row(const float* p, int stride) {
#pragma clang fp contract(off)
    const float p120 = np_block_sq(p, stride, 1,   120);
    const float p64  = np_block_sq(p, stride, 121, 64);
    const float p71  = np_block_sq(p, stride, 185, 71);
    const float s135 = p64 + p71;
    const float s255 = p120 + s135;
    return sq_at(p, 0, stride) + s255;
}

// ---------------- merged prologue: xsq (128 blk) + esq (4 blk) + tr4 (256 blk)
__global__ void vq_prologue_kernel(const float* __restrict__ x, const float* __restrict__ cb,
                                   float* __restrict__ xsq, float* __restrict__ esq,
                                   float4* __restrict__ et4) {
    const int bid = blockIdx.x;
    if (bid < 128) {                                   // xsq: 32768 rows
        const int n = bid * 256 + threadIdx.x;
        const float* p = x + ((size_t)(n >> 10)) * (DIMS * 1024) + (n & 1023);
        xsq[n] = np_sumsq_row(p, 1024);
    } else if (bid < 132) {                            // esq: 1024 codes
        const int c = (bid - 128) * 256 + threadIdx.x;
        esq[c] = np_sumsq_row(cb + (size_t)c * DIMS, 1);
    } else {                                           // et4[dk][c] panel transpose
        const int idx = (bid - 132) * 256 + threadIdx.x;   // 65536 = 64 dk x 1024 c
        const int dk  = idx & 63;
        const int c   = idx >> 6;
        const float4 v = *reinterpret_cast<const float4*>(cb + (size_t)c * DIMS + dk * 4);
        et4[(size_t)dk * K_CODES + c] = v;
    }
}

// ---------------- main v7: 4 codes/lane x 8 rows — TLP-first small tile -----
// Design point (from R5-R11 evidence): every config with <=4 waves/SIMD
// stalls 25-35% on load latency regardless of ILP tricks. This tile keeps
// the natural register footprint <=64 VGPR (acc 32 + e 16 + temps), which
// per the 64/128/256 occupancy buckets allows 8 waves/SIMD; grid = 4096
// blocks (16/CU) so residency is register-bound, not grid-bound. e is
// single-buffered (L2-resident ~250cy) and x via wave-uniform s_load with
// 21-bit imm offsets (zero VALU addressing) — latency covered by TLP.
// FMA chain per (row,code): one accumulator, strictly ascending d (dk asc,
// dd asc) -> bitwise identical to the np/BLAS reference order.
__global__ __launch_bounds__(256, 2)
void vq_main7_kernel(const float* __restrict__ x, const float4* __restrict__ et4,
                     const float* __restrict__ esq, const float* __restrict__ xsq,
                     float2* __restrict__ cand) {
    const int wid  = __builtin_amdgcn_readfirstlane((int)(threadIdx.x >> 6));
    const int lane = threadIdx.x & 63;
    const int W     = blockIdx.x * 4 + wid;        // 0..16383
    const int g     = W & (NGROUPS - 1);           // code group of 256
    const int slice = W >> 2;                      // 0..4095 row slice
    const int c0    = g * 256 + lane;              // lane codes: c0 + 64*j, j=0..3
    const int row_base = slice * ROWS_PER_WAVE;    // 8 | 1024 -> one image
    const int b    = row_base >> 10;
    const int hw0  = row_base & 1023;
    const float* xb = x + (size_t)b * (DIMS * 1024) + hw0;   // + d*1024 + r

    const float esq0 = esq[c0];
    const float esq1 = esq[c0 + 64];
    const float esq2 = esq[c0 + 128];
    const float esq3 = esq[c0 + 192];

    float acc0[RP], acc1[RP], acc2[RP], acc3[RP];
    #pragma unroll
    for (int r = 0; r < RP; ++r) { acc0[r] = 0.0f; acc1[r] = 0.0f; acc2[r] = 0.0f; acc3[r] = 0.0f; }

    for (int dk = 0; dk < DIMS / 4; ++dk) {
        // e: 4 coalesced dwordx4 loads; v-offset (c0*16) loop-invariant,
        // base bump is SALU, +{0,1024,2048,3072}B fold into imm offsets.
        const float4* ep = et4 + (size_t)dk * K_CODES;
        const float4 e0 = ep[c0];
        const float4 e1 = ep[c0 + 64];
        const float4 e2 = ep[c0 + 128];
        const float4 e3 = ep[c0 + 192];

        // per dim: 8 wave-uniform x loads (s_load, imm offsets) feed 32 FMAs.
        #pragma unroll
        for (int dd = 0; dd < 4; ++dd) {
            float xv[RP];
            #pragma unroll
            for (int r = 0; r < RP; ++r)
                xv[r] = xb[(size_t)(dk * 4 + dd) * 1024 + r];
            const float ev0 = (dd == 0) ? e0.x : (dd == 1) ? e0.y : (dd == 2) ? e0.z : e0.w;
            const float ev1 = (dd == 0) ? e1.x : (dd == 1) ? e1.y : (dd == 2) ? e1.z : e1.w;
            const float ev2 = (dd == 0) ? e2.x : (dd == 1) ? e2.y : (dd == 2) ? e2.z : e2.w;
            const float ev3 = (dd == 0) ? e3.x : (dd == 1) ? e3.y : (dd == 2) ? e3.z : e3.w;
            #pragma unroll
            for (int r = 0; r < RP; ++r) acc0[r] = fmaf(xv[r], ev0, acc0[r]);
            #pragma unroll
            for (int r = 0; r < RP; ++r) acc1[r] = fmaf(xv[r], ev1, acc1[r]);
            #pragma unroll
            for (int r = 0; r < RP; ++r) acc2[r] = fmaf(xv[r], ev2, acc2[r]);
            #pragma unroll
            for (int r = 0; r < RP; ++r) acc3[r] = fmaf(xv[r], ev3, acc3[r]);
        }
    }

    // epilogue: d2 = fl(fl(x_sq - 2*dot) + e_sq), exact np op order;
    // in-lane combine ascending c (strict < -> lower code wins ties),
    // then exact first-index 64-lane lexmin butterfly.
    {
#pragma clang fp contract(off)
        float keepv = 0.0f; int keepc = 0;
        #pragma unroll
        for (int r = 0; r < RP; ++r) {
            const float xs_r = xsq[row_base + r];            // uniform
            const float v0 = (xs_r - 2.0f * acc0[r]) + esq0;
            const float v1 = (xs_r - 2.0f * acc1[r]) + esq1;
            const float v2 = (xs_r - 2.0f * acc2[r]) + esq2;
            const float v3 = (xs_r - 2.0f * acc3[r]) + esq3;
            float bv = v0; int bc = c0;
            if (v1 < bv) { bv = v1; bc = c0 + 64; }
            if (v2 < bv) { bv = v2; bc = c0 + 128; }
            if (v3 < bv) { bv = v3; bc = c0 + 192; }
            #pragma unroll
            for (int off = 1; off < 64; off <<= 1) {
                const float ov = __shfl_xor(bv, off, 64);
                const int   oc = __shfl_xor(bc, off, 64);
                if (ov < bv || (ov == bv && oc < bc)) { bv = ov; bc = oc; }
            }
            if (lane == r) { keepv = bv; keepc = bc; }       // lane r keeps row r
        }
        if (lane < RP) {
            cand[(size_t)g * NROWS + row_base + lane] =
                make_float2(keepv, __int_as_float(keepc));
        }
    }
}

// ---------------- cross-group lexmin reduce (groups ascending in code) ------
__global__ void vq_reduce_kernel(const float2* __restrict__ cand, int* __restrict__ out) {
    const int row = blockIdx.x * 256 + threadIdx.x;
    float2 p = cand[row];
    float bv = p.x; int bc = __float_as_int(p.y);
    #pragma unroll
    for (int gg = 1; gg < NGROUPS; ++gg) {
        const float2 q = cand[(size_t)gg * NROWS + row];
        const float v = q.x; const int qc = __float_as_int(q.y);
        if (v < bv || (v == bv && qc < bc)) { bv = v; bc = qc; }
    }
    out[row] = bc;
}

// ===========================================================================
// Fallback path (round-2 kernel, verified passing) — used if ws too small.
// ===========================================================================
#define BM      64
#define BN      128
#define DK      32
#define PITCH   36

__global__ void vq_xsq_kernel(const float* __restrict__ x, float* __restrict__ xsq) {
    const int n = blockIdx.x * 256 + threadIdx.x;
    const float* p = x + ((size_t)(n >> 10)) * (DIMS * 1024) + (n & 1023);
    xsq[n] = np_sumsq_row(p, 1024);
}

__global__ void vq_esq_kernel(const float* __restrict__ cb, float* __restrict__ esq) {
    const int c = blockIdx.x * 256 + threadIdx.x;
    esq[c] = np_sumsq_row(cb + (size_t)c * DIMS, 1);
}

__global__ __launch_bounds__(256, 2)
void vq_main_kernel(const float* __restrict__ x, const float* __restrict__ cb,
                    const float* __restrict__ esq, const float* __restrict__ xsq,
                    int* __restrict__ out) {
    __shared__ float xs[BM * PITCH];

    const int t   = threadIdx.x;
    const int tc  = t & 15;
    const int tr  = t >> 4;
    const int row0 = blockIdx.x * BM;
    const int b   = row0 >> 10;
    const int hw0 = row0 & 1023;
    const float* xb = x + (size_t)b * DIMS * 1024 + hw0;

    float xsqr[4];
    #pragma unroll
    for (int i = 0; i < 4; ++i) xsqr[i] = xsq[row0 + tr * 4 + i];

    float bestv[4];
    int   bestc[4];
    #pragma unroll
    for (int i = 0; i < 4; ++i) { bestv[i] = 3.4e38f; bestc[i] = 0; }

    for (int cc = 0; cc < K_CODES / BN; ++cc) {
        const float* ep[8];
        #pragma unroll
        for (int j = 0; j < 8; ++j)
            ep[j] = cb + (size_t)(cc * BN + tc + 16 * j) * DIMS;

        float acc[4][8];
        #pragma unroll
        for (int i = 0; i < 4; ++i)
            #pragma unroll
            for (int j = 0; j < 8; ++j) acc[i][j] = 0.0f;

        for (int dk = 0; dk < DIMS / DK; ++dk) {
            __syncthreads();
            #pragma unroll
            for (int ii = 0; ii < 2; ++ii) {
                const int li = t + 256 * ii;
                const int d  = (li >> 2) & 31;
                const int h4 = (li & 3) | ((li >> 7) << 2);
                const float4 v = *reinterpret_cast<const float4*>(
                    xb + (size_t)(dk * DK + d) * 1024 + h4 * 4);
                xs[(h4 * 4 + 0) * PITCH + d] = v.x;
                xs[(h4 * 4 + 1) * PITCH + d] = v.y;
                xs[(h4 * 4 + 2) * PITCH + d] = v.z;
                xs[(h4 * 4 + 3) * PITCH + d] = v.w;
            }
            __syncthreads();

            #pragma unroll
            for (int d4 = 0; d4 < DK; d4 += 4) {
                float4 xv[4];
                #pragma unroll
                for (int i = 0; i < 4; ++i)
                    xv[i] = *reinterpret_cast<const float4*>(&xs[(tr * 4 + i) * PITCH + d4]);
                float4 ev[8];
                #pragma unroll
                for (int j = 0; j < 8; ++j)
                    ev[j] = *reinterpret_cast<const float4*>(ep[j] + dk * DK + d4);
                #pragma unroll
                for (int i = 0; i < 4; ++i) {
                    #pragma unroll
                    for (int j = 0; j < 8; ++j) {
                        acc[i][j] = fmaf(xv[i].x, ev[j].x, acc[i][j]);
                        acc[i][j] = fmaf(xv[i].y, ev[j].y, acc[i][j]);
                        acc[i][j] = fmaf(xv[i].z, ev[j].z, acc[i][j]);
                        acc[i][j] = fmaf(xv[i].w, ev[j].w, acc[i][j]);
                    }
                }
            }
        }

        {
#pragma clang fp contract(off)
            #pragma unroll
            for (int j = 0; j < 8; ++j) {
                const int c = cc * BN + tc + 16 * j;
                const float es = esq[c];
                #pragma unroll
                for (int i = 0; i < 4; ++i) {
                    const float t3 = xsqr[i] - 2.0f * acc[i][j];
                    const float v  = t3 + es;
                    if (v < bestv[i]) { bestv[i] = v; bestc[i] = c; }
                }
            }
        }
    }

    __syncthreads();
    float* rv = xs;
    int*   rc = reinterpret_cast<int*>(xs + BM * 16);
    #pragma unroll
    for (int i = 0; i < 4; ++i) {
        const int r = tr * 4 + i;
        rv[r * 16 + tc] = bestv[i];
        rc[r * 16 + tc] = bestc[i];
    }
    __syncthreads();
    if (t < BM) {
        float bv = rv[t * 16];
        int   bc = rc[t * 16];
        #pragma unroll
        for (int k = 1; k < 16; ++k) {
            const float v = rv[t * 16 + k];
            const int   cidx = rc[t * 16 + k];
            if (v < bv || (v == bv && cidx < bc)) { bv = v; bc = cidx; }
        }
        out[row0 + t] = bc;
    }
}

// ===========================================================================
extern "C" void kernel_launch(void* const* d_in, const int* in_sizes, int n_in,
                              void* d_out, int out_size, void* d_ws, size_t ws_size,
                              hipStream_t stream) {
    const float* x  = (const float*)d_in[0];   // [32, 256, 32, 32]
    const float* cb = (const float*)d_in[1];   // [1024, 256]
    int* out = (int*)d_out;                    // [32768] int32
    float* ws = (float*)d_ws;

    if (ws_size >= WS_NEED_BYTES) {
        float4* et4  = (float4*)(ws + WS_ET);
        float*  esq  = ws + WS_ESQ;
        float*  xsq  = ws + WS_XSQ;
        float2* cand = (float2*)(ws + WS_CAND);

        vq_prologue_kernel<<<128 + 4 + 256, 256, 0, stream>>>(x, cb, xsq, esq, et4);
        vq_main7_kernel<<<(NROWS / ROWS_PER_WAVE) * NGROUPS / 4, 256, 0, stream>>>(
            x, et4, esq, xsq, cand);
        vq_reduce_kernel<<<NROWS / 256, 256, 0, stream>>>(cand, out);
    } else {
        float* esq = ws;
        float* xsq = ws + K_CODES;
        vq_xsq_kernel<<<NROWS / 256, 256, 0, stream>>>(x, xsq);
        vq_esq_kernel<<<K_CODES / 256, 256, 0, stream>>>(cb, esq);
        vq_main_kernel<<<NROWS / BM, 256, 0, stream>>>(x, cb, esq, xsq, out);
    }
}